// Round 4
// baseline (403.722 us; speedup 1.0000x reference)
//
#include <hip/hip_runtime.h>
#include <cmath>

// ---------------------------------------------------------------------------
// 3-layer GCN, atomic-free, fused per layer, bf16 intermediates.
// Per call: CSR build (hist -> scan -> fill), x -> bf16, then per layer:
//   h = relu(gather_sum(in_bf16) @ W + b)   [bf16 out]   (layers 1,2)
//   out = log_softmax(gather_sum(h2) @ W3 + b3)  [fp32 out]
// Gather rows are 128B (64 x bf16) = 1 L2 line; accumulate fp32.
// ---------------------------------------------------------------------------

#define SCAN_B 256

__device__ __forceinline__ float wave_max64(float v) {
#pragma unroll
  for (int off = 32; off >= 1; off >>= 1) v = fmaxf(v, __shfl_xor(v, off, 64));
  return v;
}
__device__ __forceinline__ float wave_sum64(float v) {
#pragma unroll
  for (int off = 32; off >= 1; off >>= 1) v += __shfl_xor(v, off, 64);
  return v;
}

__device__ __forceinline__ unsigned short f2bf(float x) {   // RNE
  unsigned int u = __float_as_uint(x);
  unsigned int r = (u + 0x7FFFu + ((u >> 16) & 1u)) >> 16;
  return (unsigned short)r;
}
__device__ __forceinline__ float bflo(unsigned int u) { return __uint_as_float(u << 16); }
__device__ __forceinline__ float bfhi(unsigned int u) { return __uint_as_float(u & 0xFFFF0000u); }

// ---------------- CSR build ----------------
__global__ void hist_k(const int* __restrict__ dsti, int* __restrict__ cnt, int ne) {
  int i = blockIdx.x * blockDim.x + threadIdx.x;
  int st = gridDim.x * blockDim.x;
  for (int e = i; e < ne; e += st) atomicAdd(&cnt[dsti[e]], 1);
}

__global__ void scan1_k(int* __restrict__ cnt, int* __restrict__ bsum, int n) {
  __shared__ int sh[SCAN_B];
  int t = threadIdx.x, i = blockIdx.x * SCAN_B + t;
  int x = (i < n) ? cnt[i] : 0;
  sh[t] = x; __syncthreads();
  for (int o = 1; o < SCAN_B; o <<= 1) {
    int v = (t >= o) ? sh[t - o] : 0; __syncthreads();
    sh[t] += v; __syncthreads();
  }
  if (i < n) cnt[i] = sh[t] - x;
  if (t == SCAN_B - 1) bsum[blockIdx.x] = sh[t];
}

__global__ void scan2_k(int* __restrict__ bsum, int nb) {
  __shared__ int sh[512];
  int t = threadIdx.x;
  int x = (t < nb) ? bsum[t] : 0;
  sh[t] = x; __syncthreads();
  for (int o = 1; o < 512; o <<= 1) {
    int v = (t >= o) ? sh[t - o] : 0; __syncthreads();
    sh[t] += v; __syncthreads();
  }
  if (t < nb) bsum[t] = sh[t] - x;
}

__global__ void scan3_k(const int* __restrict__ cnt, const int* __restrict__ bsum,
                        int* __restrict__ row_off, int* __restrict__ cursor, int n, int e) {
  int i = blockIdx.x * SCAN_B + threadIdx.x;
  if (i < n) {
    int v = cnt[i] + bsum[i / SCAN_B];
    row_off[i] = v; cursor[i] = v;
  }
  if (i == 0) row_off[n] = e;
}

__global__ void fill_k(const int* __restrict__ srci, const int* __restrict__ dsti,
                       int* __restrict__ cursor, int* __restrict__ ssrc, int ne) {
  int i = blockIdx.x * blockDim.x + threadIdx.x;
  int st = gridDim.x * blockDim.x;
  for (int e = i; e < ne; e += st) {
    int p = atomicAdd(&cursor[dsti[e]], 1);
    ssrc[p] = srci[e];
  }
}

// ---------------- fp32 -> bf16 ----------------
__global__ void cvt_bf16_k(const float* __restrict__ in, unsigned short* __restrict__ outp,
                           int n4) {   // n4 = total elems / 4
  int i = blockIdx.x * blockDim.x + threadIdx.x;
  int st = gridDim.x * blockDim.x;
  for (int j = i; j < n4; j += st) {
    float4 v = ((const float4*)in)[j];
    ushort4 o;
    o.x = f2bf(v.x); o.y = f2bf(v.y); o.z = f2bf(v.z); o.w = f2bf(v.w);
    ((ushort4*)outp)[j] = o;
  }
}

// ---------------- fused gather + GEMM (+relu->bf16 | +log_softmax->fp32) ---
// One wave per node. Gather layout: eg = lane>>4 (edge slot 0..3),
// f = lane&15 (8-byte chunk = 4 bf16 features 4f..4f+3). Epilogue: lane=col.
template <int DOUT, bool LS>
__launch_bounds__(256)
__global__ void fused_gcn_k(const unsigned short* __restrict__ in,
                            const int* __restrict__ row_off, const int* __restrict__ ssrc,
                            const float* __restrict__ Wm, const float* __restrict__ bin,
                            void* __restrict__ outp, int n) {
  const int lane  = threadIdx.x & 63;
  const int wslot = threadIdx.x >> 6;
  const int eg    = lane >> 4;
  const int f     = lane & 15;
  const int col   = lane < DOUT ? lane : DOUT - 1;

  // W column pinned in 64 VGPRs (asm "+v" blocks rematerialization).
  float w[64];
#pragma unroll
  for (int k = 0; k < 64; ++k) w[k] = Wm[k * DOUT + col];
#pragma unroll
  for (int k = 0; k < 64; ++k) asm volatile("" : "+v"(w[k]));
  const float bcol = bin[col];

  __shared__ float4 sbuf[4 * 16];   // one 64-float row per wave

  const uint2* in2 = (const uint2*)in;   // row = 16 uint2 (128B)
  int wave = (int)((blockIdx.x * blockDim.x + threadIdx.x) >> 6);
  int nw   = (int)((gridDim.x * blockDim.x) >> 6);

  for (int v = wave; v < n; v += nw) {
    const int start = row_off[v], end = row_off[v + 1];
    float4 a0 = make_float4(0.f, 0.f, 0.f, 0.f);
    float4 a1 = make_float4(0.f, 0.f, 0.f, 0.f);
    for (int c = start; c < end; c += 8) {
      const int e0 = c + eg, e1 = e0 + 4;
      uint2 q0 = make_uint2(0u, 0u), q1 = make_uint2(0u, 0u);
      if (e0 < end) q0 = in2[(size_t)ssrc[e0] * 16 + f];
      if (e1 < end) q1 = in2[(size_t)ssrc[e1] * 16 + f];
      a0.x += bflo(q0.x); a0.y += bfhi(q0.x); a0.z += bflo(q0.y); a0.w += bfhi(q0.y);
      a1.x += bflo(q1.x); a1.y += bfhi(q1.x); a1.z += bflo(q1.y); a1.w += bfhi(q1.y);
    }
    float4 a = make_float4(a0.x + a1.x, a0.y + a1.y, a0.z + a1.z, a0.w + a1.w);
    // butterfly across the 4 edge slots (xor 16, 32)
#pragma unroll
    for (int off = 16; off <= 32; off <<= 1) {
      a.x += __shfl_xor(a.x, off, 64);
      a.y += __shfl_xor(a.y, off, 64);
      a.z += __shfl_xor(a.z, off, 64);
      a.w += __shfl_xor(a.w, off, 64);
    }
    if (lane < 16) sbuf[wslot * 16 + lane] = a;   // wave-private, no barrier
    float d0 = bcol, d1 = 0.f, d2 = 0.f, d3 = 0.f;  // 4 chains, 16 deep
#pragma unroll
    for (int k4 = 0; k4 < 16; ++k4) {
      const float4 s4 = sbuf[wslot * 16 + k4];    // wave-uniform broadcast
      d0 = fmaf(s4.x, w[4 * k4 + 0], d0);
      d1 = fmaf(s4.y, w[4 * k4 + 1], d1);
      d2 = fmaf(s4.z, w[4 * k4 + 2], d2);
      d3 = fmaf(s4.w, w[4 * k4 + 3], d3);
    }
    const float dot = (d0 + d1) + (d2 + d3);
    if (!LS) {
      ((unsigned short*)outp)[(size_t)v * 64 + lane] = f2bf(fmaxf(dot, 0.f));
    } else {
      float val = lane < DOUT ? dot : -INFINITY;
      float m   = wave_max64(val);
      float ex  = lane < DOUT ? __expf(val - m) : 0.f;
      float s   = wave_sum64(ex);
      if (lane < DOUT) ((float*)outp)[(size_t)v * DOUT + lane] = val - m - __logf(s);
    }
  }
}

extern "C" void kernel_launch(void* const* d_in, const int* in_sizes, int n_in,
                              void* d_out, int out_size, void* d_ws, size_t ws_size,
                              hipStream_t stream) {
  const float* x  = (const float*)d_in[0];
  const int*   ei = (const int*)d_in[1];   // [2, E] int32, row-major
  const float* W1 = (const float*)d_in[2];
  const float* b1 = (const float*)d_in[3];
  const float* W2 = (const float*)d_in[4];
  const float* b2 = (const float*)d_in[5];
  const float* W3 = (const float*)d_in[6];
  const float* b3 = (const float*)d_in[7];
  float* outp = (float*)d_out;

  const int n  = in_sizes[0] / 64;   // 100000
  const int ne = in_sizes[1] / 2;    // 800000
  const int* srci = ei;
  const int* dsti = ei + ne;

  const size_t N64 = (size_t)n * 64;
  unsigned short* xb   = (unsigned short*)d_ws;   // N*64 bf16
  unsigned short* bufA = xb + N64;                // N*64 bf16 (h1)
  unsigned short* bufB = bufA + N64;              // N*64 bf16 (h2)
  int* cnt      = (int*)(bufB + N64);             // N
  int* row_off  = cnt + n;                        // N+1
  int* cursor   = row_off + n + 1;                // N
  int* bsum     = cursor + n;                     // 512
  int* ssrc     = bsum + 512;                     // E

  const int TB = 256;
  const int nscan = (n + SCAN_B - 1) / SCAN_B;
  const int eblocks = (ne + TB - 1) / TB;
  const int fus_blocks = 8192;                    // ~3 nodes/wave grid-stride

  // ---- CSR build (per call; d_ws is re-poisoned) ----
  hipMemsetAsync(cnt, 0, (size_t)n * sizeof(int), stream);
  hist_k<<<eblocks, TB, 0, stream>>>(dsti, cnt, ne);
  scan1_k<<<nscan, SCAN_B, 0, stream>>>(cnt, bsum, n);
  scan2_k<<<1, 512, 0, stream>>>(bsum, nscan);
  scan3_k<<<nscan, SCAN_B, 0, stream>>>(cnt, bsum, row_off, cursor, n, ne);
  fill_k<<<eblocks, TB, 0, stream>>>(srci, dsti, cursor, ssrc, ne);

  // ---- x -> bf16 ----
  cvt_bf16_k<<<4096, TB, 0, stream>>>(x, xb, (int)(N64 / 4));

  // ---- fused layers ----
  fused_gcn_k<64, false><<<fus_blocks, TB, 0, stream>>>(xb,   row_off, ssrc, W1, b1, bufA, n);
  fused_gcn_k<64, false><<<fus_blocks, TB, 0, stream>>>(bufA, row_off, ssrc, W2, b2, bufB, n);
  fused_gcn_k<47, true ><<<fus_blocks, TB, 0, stream>>>(bufB, row_off, ssrc, W3, b3, outp, n);
}

// Round 5
// 301.661 us; speedup vs baseline: 1.3383x; 1.3383x over previous
//
#include <hip/hip_runtime.h>
#include <cmath>

// ---------------------------------------------------------------------------
// 3-layer GCN, atomic-free, bf16 data path, MFMA epilogue.
// Per call: CSR build (hist+cvt -> scan1 -> scan23 -> fill), then per layer
// one fused kernel: quarter-wave gather-sum of 16 nodes -> bf16 rows in LDS
// -> mfma_f32_16x16x32_bf16 x (2K x NT tiles) -> bias (+relu->bf16 store, or
// +log_softmax->fp32 store).  __launch_bounds__(256,4): 128-VGPR cap, W frags
// stay in registers (R4's 52-VGPR scratch spill was the hidden bottleneck).
// ---------------------------------------------------------------------------

#define SCAN_B 256

typedef __attribute__((ext_vector_type(8))) short bf8;   // 8 x bf16 (4 VGPR)
typedef __attribute__((ext_vector_type(4))) float f4;    // MFMA accumulator

__device__ __forceinline__ unsigned int f2bf(float x) {  // RNE
  unsigned int u = __float_as_uint(x);
  return (u + 0x7FFFu + ((u >> 16) & 1u)) >> 16;
}
__device__ __forceinline__ float bflo(unsigned int u) { return __uint_as_float(u << 16); }
__device__ __forceinline__ float bfhi(unsigned int u) { return __uint_as_float(u & 0xFFFF0000u); }

// ---------------- CSR build ----------------
__global__ void hist_cvt_k(const int* __restrict__ dsti, int* __restrict__ cnt, int ne,
                           const float* __restrict__ x, unsigned short* __restrict__ xb,
                           int n4) {
  int i = blockIdx.x * blockDim.x + threadIdx.x;
  int st = gridDim.x * blockDim.x;
  for (int e = i; e < ne; e += st) atomicAdd(&cnt[dsti[e]], 1);
  for (int j = i; j < n4; j += st) {
    float4 v = ((const float4*)x)[j];
    ushort4 o;
    o.x = (unsigned short)f2bf(v.x); o.y = (unsigned short)f2bf(v.y);
    o.z = (unsigned short)f2bf(v.z); o.w = (unsigned short)f2bf(v.w);
    ((ushort4*)xb)[j] = o;
  }
}

__global__ void scan1_k(int* __restrict__ cnt, int* __restrict__ bsum, int n) {
  __shared__ int sh[SCAN_B];
  int t = threadIdx.x, i = blockIdx.x * SCAN_B + t;
  int x = (i < n) ? cnt[i] : 0;
  sh[t] = x; __syncthreads();
  for (int o = 1; o < SCAN_B; o <<= 1) {
    int v = (t >= o) ? sh[t - o] : 0; __syncthreads();
    sh[t] += v; __syncthreads();
  }
  if (i < n) cnt[i] = sh[t] - x;           // exclusive within block
  if (t == SCAN_B - 1) bsum[blockIdx.x] = sh[t];
}

// block b: pref = sum(bsum[0..b)), row_off[i] = cnt[i] + pref  (scan2+scan3)
__global__ void scan23_k(const int* __restrict__ cnt, const int* __restrict__ bsum,
                         int* __restrict__ row_off, int* __restrict__ cursor,
                         int n, int ne) {
  __shared__ int sh[SCAN_B];
  const int b = blockIdx.x, t = threadIdx.x;
  int s = 0;
  for (int j = t; j < b; j += SCAN_B) s += bsum[j];
  sh[t] = s; __syncthreads();
  for (int o = SCAN_B / 2; o > 0; o >>= 1) {
    if (t < o) sh[t] += sh[t + o];
    __syncthreads();
  }
  const int pref = sh[0];
  const int i = b * SCAN_B + t;
  if (i < n) { int v = cnt[i] + pref; row_off[i] = v; cursor[i] = v; }
  if (b == 0 && t == 0) row_off[n] = ne;
}

__global__ void fill_k(const int* __restrict__ srci, const int* __restrict__ dsti,
                       int* __restrict__ cursor, int* __restrict__ ssrc, int ne) {
  int i = blockIdx.x * blockDim.x + threadIdx.x;
  int st = gridDim.x * blockDim.x;
  for (int e = i; e < ne; e += st) {
    int p = atomicAdd(&cursor[dsti[e]], 1);
    ssrc[p] = srci[e];
  }
}

// ---------------- fused gather + MFMA GEMM (+relu | +log_softmax) ----------
// One wave per 16-node tile. Gather: quarter q, lane f=lane&15 owns 8B of the
// 128B bf16 row; q handles nodes q*4+r. Rows -> LDS (144B stride: 16B-aligned
// for b128 A-frag reads, <=2-way banks). MFMA 16x16x32 bf16: A[m=lane&15]
// [k=quad*8+j], B[n=lane&15][k=quad*8+j], C col=lane&15 row=quad*4+reg.
template <int DOUT, bool LS>
__launch_bounds__(256, 4)
__global__ void fused_k(const unsigned short* __restrict__ in,
                        const int* __restrict__ row_off, const int* __restrict__ ssrc,
                        const float* __restrict__ Wm, const float* __restrict__ bin,
                        void* __restrict__ outp, int n) {
  constexpr int NT = (DOUT + 15) / 16;
  const int lane  = threadIdx.x & 63;
  const int wslot = threadIdx.x >> 6;
  const int quad  = lane >> 4;
  const int f16i  = lane & 15;

  __shared__ char smem_raw[4][16 * 144];
  char* my = smem_raw[wslot];

  // B fragments: W (bf16) in registers, 2 K-steps x NT col tiles.
  bf8 bfr[2][NT];
#pragma unroll
  for (int s = 0; s < 2; ++s)
#pragma unroll
    for (int t = 0; t < NT; ++t) {
      const int c = t * 16 + f16i;
#pragma unroll
      for (int j = 0; j < 8; ++j) {
        const int k = s * 32 + quad * 8 + j;
        float wv = (c < DOUT) ? Wm[k * DOUT + c] : 0.f;
        bfr[s][t][j] = (short)f2bf(wv);
      }
    }
  float bc[NT];
#pragma unroll
  for (int t = 0; t < NT; ++t) {
    const int c = t * 16 + f16i;
    bc[t] = (c < DOUT) ? bin[c] : 0.f;
  }

  const uint2* in2 = (const uint2*)in;     // bf16 row = 16 x uint2 (128B)
  const int wid = (int)((blockIdx.x * blockDim.x + threadIdx.x) >> 6);
  const int nwv = (int)((gridDim.x * blockDim.x) >> 6);
  const int ntiles = (n + 15) >> 4;

  for (int tile = wid; tile < ntiles; tile += nwv) {
    const int v0 = tile << 4;
    // ---- gather 16 node-sums -> bf16 rows in LDS ----
#pragma unroll
    for (int r = 0; r < 4; ++r) {
      const int m = quad * 4 + r;
      const int v = v0 + m;
      int start = 0, end = 0;
      if (v < n) { start = row_off[v]; end = row_off[v + 1]; }
      float4 a = make_float4(0.f, 0.f, 0.f, 0.f);
      for (int c = start; c < end; c += 2) {
        const int s0 = ssrc[c];
        const bool h1 = (c + 1) < end;
        const int s1 = h1 ? ssrc[c + 1] : s0;
        uint2 q0 = in2[(size_t)s0 * 16 + f16i];
        uint2 q1 = h1 ? in2[(size_t)s1 * 16 + f16i] : make_uint2(0u, 0u);
        a.x += bflo(q0.x) + bflo(q1.x);
        a.y += bfhi(q0.x) + bfhi(q1.x);
        a.z += bflo(q0.y) + bflo(q1.y);
        a.w += bfhi(q0.y) + bfhi(q1.y);
      }
      uint2 p;
      p.x = f2bf(a.x) | (f2bf(a.y) << 16);
      p.y = f2bf(a.z) | (f2bf(a.w) << 16);
      *(uint2*)(my + m * 144 + f16i * 8) = p;   // 8B-aligned, <=2-way banks
    }
    asm volatile("s_waitcnt lgkmcnt(0)" ::: "memory");  // cross-lane LDS RAW

    // ---- MFMA: [16 x 64] @ [64 x DOUT] ----
    bf8 a0 = *(const bf8*)(my + f16i * 144 + quad * 16);        // K 0..31
    bf8 a1 = *(const bf8*)(my + f16i * 144 + quad * 16 + 64);   // K 32..63
    f4 acc[NT];
#pragma unroll
    for (int t = 0; t < NT; ++t) {
      f4 z = {0.f, 0.f, 0.f, 0.f};
      acc[t] = __builtin_amdgcn_mfma_f32_16x16x32_bf16(a0, bfr[0][t], z, 0, 0, 0);
      acc[t] = __builtin_amdgcn_mfma_f32_16x16x32_bf16(a1, bfr[1][t], acc[t], 0, 0, 0);
    }

    // ---- epilogue ----
    if (!LS) {
      unsigned short* ob = (unsigned short*)outp;
#pragma unroll
      for (int t = 0; t < NT; ++t)
#pragma unroll
        for (int j = 0; j < 4; ++j) {
          const int v = v0 + quad * 4 + j;
          if (v < n) {
            float val = acc[t][j] + bc[t];
            ob[(size_t)v * 64 + t * 16 + f16i] =
                (unsigned short)f2bf(fmaxf(val, 0.f));
          }
        }
    } else {
      float* ob = (float*)outp;
      float val[NT][4];
#pragma unroll
      for (int t = 0; t < NT; ++t)
#pragma unroll
        for (int j = 0; j < 4; ++j) val[t][j] = acc[t][j] + bc[t];
#pragma unroll
      for (int j = 0; j < 4; ++j) {
        float mx = -INFINITY;
#pragma unroll
        for (int t = 0; t < NT; ++t)
          if (t * 16 + f16i < DOUT) mx = fmaxf(mx, val[t][j]);
#pragma unroll
        for (int o = 1; o <= 8; o <<= 1) mx = fmaxf(mx, __shfl_xor(mx, o, 64));
        float sm = 0.f;
#pragma unroll
        for (int t = 0; t < NT; ++t)
          if (t * 16 + f16i < DOUT) sm += __expf(val[t][j] - mx);
#pragma unroll
        for (int o = 1; o <= 8; o <<= 1) sm += __shfl_xor(sm, o, 64);
        const float lse = mx + __logf(sm);
        const int v = v0 + quad * 4 + j;
        if (v < n) {
#pragma unroll
          for (int t = 0; t < NT; ++t) {
            const int c = t * 16 + f16i;
            if (c < DOUT) ob[(size_t)v * DOUT + c] = val[t][j] - lse;
          }
        }
      }
    }
  }
}

extern "C" void kernel_launch(void* const* d_in, const int* in_sizes, int n_in,
                              void* d_out, int out_size, void* d_ws, size_t ws_size,
                              hipStream_t stream) {
  const float* x  = (const float*)d_in[0];
  const int*   ei = (const int*)d_in[1];   // [2, E] int32, row-major
  const float* W1 = (const float*)d_in[2];
  const float* b1 = (const float*)d_in[3];
  const float* W2 = (const float*)d_in[4];
  const float* b2 = (const float*)d_in[5];
  const float* W3 = (const float*)d_in[6];
  const float* b3 = (const float*)d_in[7];
  float* outp = (float*)d_out;

  const int n  = in_sizes[0] / 64;   // 100000
  const int ne = in_sizes[1] / 2;    // 800000
  const int* srci = ei;
  const int* dsti = ei + ne;

  const size_t N64 = (size_t)n * 64;
  unsigned short* xb   = (unsigned short*)d_ws;   // N*64 bf16
  unsigned short* bufA = xb + N64;                // N*64 bf16 (h1)
  unsigned short* bufB = bufA + N64;              // N*64 bf16 (h2)
  int* cnt      = (int*)(bufB + N64);             // N
  int* row_off  = cnt + n;                        // N+1
  int* cursor   = row_off + n + 1;                // N
  int* bsum     = cursor + n;                     // 512
  int* ssrc     = bsum + 512;                     // E

  const int TB = 256;
  const int nscan = (n + SCAN_B - 1) / SCAN_B;
  const int fus_blocks = 1568;                    // ~1 tile/wave (6250 tiles)

  // ---- CSR build + x->bf16 ----
  hipMemsetAsync(cnt, 0, (size_t)n * sizeof(int), stream);
  hist_cvt_k<<<2048, TB, 0, stream>>>(dsti, cnt, ne, x, xb, (int)(N64 / 4));
  scan1_k<<<nscan, SCAN_B, 0, stream>>>(cnt, bsum, n);
  scan23_k<<<nscan, SCAN_B, 0, stream>>>(cnt, bsum, row_off, cursor, n, ne);
  fill_k<<<2048, TB, 0, stream>>>(srci, dsti, cursor, ssrc, ne);

  // ---- fused layers ----
  fused_k<64, false><<<fus_blocks, TB, 0, stream>>>(xb,   row_off, ssrc, W1, b1, bufA, n);
  fused_k<64, false><<<fus_blocks, TB, 0, stream>>>(bufA, row_off, ssrc, W2, b2, bufB, n);
  fused_k<47, true ><<<fus_blocks, TB, 0, stream>>>(bufB, row_off, ssrc, W3, b3, outp, n);
}

// Round 6
// 281.478 us; speedup vs baseline: 1.4343x; 1.0717x over previous
//
#include <hip/hip_runtime.h>
#include <cmath>

// ---------------------------------------------------------------------------
// 3-layer GCN, atomic-free aggregate, bf16 data path, MFMA epilogue.
// CSR build: hist+cvt -> scan1 -> scan23 -> bucket_k -> fillb_k.
// fill is 2-level so every ssrc/ebuf cache line is written by ONE block:
// R5's fill_k showed random 4B stores cost a full 64B HBM write each
// (52.7MB for 3.2MB of data; partials never merge across XCD L2s).
// Fused layer: quarter-wave gather-sum of 16 nodes -> bf16 rows in LDS ->
// mfma_f32_16x16x32_bf16 -> bias (+relu->bf16 | +log_softmax->fp32).
// ---------------------------------------------------------------------------

#define SCAN_B 256
#define B1_EPB 8192      // edges per bucket_k block
#define BKT_SH 8         // 256 nodes per bucket

typedef __attribute__((ext_vector_type(8))) short bf8;   // 8 x bf16 (4 VGPR)
typedef __attribute__((ext_vector_type(4))) float f4;    // MFMA accumulator

__device__ __forceinline__ unsigned int f2bf(float x) {  // RNE
  unsigned int u = __float_as_uint(x);
  return (u + 0x7FFFu + ((u >> 16) & 1u)) >> 16;
}
__device__ __forceinline__ float bflo(unsigned int u) { return __uint_as_float(u << 16); }
__device__ __forceinline__ float bfhi(unsigned int u) { return __uint_as_float(u & 0xFFFF0000u); }

// ---------------- CSR build ----------------
__global__ void hist_cvt_k(const int* __restrict__ dsti, int* __restrict__ cnt, int ne,
                           const float* __restrict__ x, unsigned short* __restrict__ xb,
                           int n4) {
  int i = blockIdx.x * blockDim.x + threadIdx.x;
  int st = gridDim.x * blockDim.x;
  for (int e = i; e < ne; e += st) atomicAdd(&cnt[dsti[e]], 1);
  for (int j = i; j < n4; j += st) {
    float4 v = ((const float4*)x)[j];
    ushort4 o;
    o.x = (unsigned short)f2bf(v.x); o.y = (unsigned short)f2bf(v.y);
    o.z = (unsigned short)f2bf(v.z); o.w = (unsigned short)f2bf(v.w);
    ((ushort4*)xb)[j] = o;
  }
}

__global__ void scan1_k(int* __restrict__ cnt, int* __restrict__ bsum, int n) {
  __shared__ int sh[SCAN_B];
  int t = threadIdx.x, i = blockIdx.x * SCAN_B + t;
  int x = (i < n) ? cnt[i] : 0;
  sh[t] = x; __syncthreads();
  for (int o = 1; o < SCAN_B; o <<= 1) {
    int v = (t >= o) ? sh[t - o] : 0; __syncthreads();
    sh[t] += v; __syncthreads();
  }
  if (i < n) cnt[i] = sh[t] - x;           // exclusive within block
  if (t == SCAN_B - 1) bsum[blockIdx.x] = sh[t];
}

// row_off[i] = cnt[i] + sum(bsum[0..block)), bcur[b] = row_off[b*256]
__global__ void scan23_k(const int* __restrict__ cnt, const int* __restrict__ bsum,
                         int* __restrict__ row_off, int* __restrict__ bcur,
                         int n, int ne) {
  __shared__ int sh[SCAN_B];
  const int b = blockIdx.x, t = threadIdx.x;
  int s = 0;
  for (int j = t; j < b; j += SCAN_B) s += bsum[j];
  sh[t] = s; __syncthreads();
  for (int o = SCAN_B / 2; o > 0; o >>= 1) {
    if (t < o) sh[t] += sh[t + o];
    __syncthreads();
  }
  const int pref = sh[0];
  const int i = b * SCAN_B + t;
  if (i < n) {
    int v = cnt[i] + pref;
    row_off[i] = v;
    if ((i & ((1 << BKT_SH) - 1)) == 0) bcur[i >> BKT_SH] = v;
  }
  if (b == 0 && t == 0) row_off[n] = ne;
}

// Level 1: scatter (src,dst) into per-bucket regions of ebuf. Per-(block,bin)
// runs are contiguous & single-CU -> partial stores merge in that CU's L2.
__global__ void bucket_k(const int* __restrict__ srci, const int* __restrict__ dsti,
                         int* __restrict__ bcur, uint2* __restrict__ ebuf,
                         int ne, int nbkt) {
  __shared__ int lhist[512], lbase[512];
  const int t = threadIdx.x;
  const int base = blockIdx.x * B1_EPB;
  const int m = min(B1_EPB, ne - base);
  for (int i = t; i < nbkt; i += 256) lhist[i] = 0;
  __syncthreads();
  for (int i = t; i < m; i += 256) atomicAdd(&lhist[dsti[base + i] >> BKT_SH], 1);
  __syncthreads();
  for (int i = t; i < nbkt; i += 256) {
    int c = lhist[i];
    lbase[i] = c ? atomicAdd(&bcur[i], c) : 0;
  }
  __syncthreads();
  for (int i = t; i < nbkt; i += 256) lhist[i] = 0;   // reuse as local cursor
  __syncthreads();
  for (int i = t; i < m; i += 256) {
    const int s = srci[base + i], d = dsti[base + i];
    const int b = d >> BKT_SH;
    const int p = lbase[b] + atomicAdd(&lhist[b], 1);
    ebuf[p] = make_uint2((unsigned)s, (unsigned)d);
  }
}

// Level 2: one block per 256-node bucket; LDS per-node cursors; writes land
// in this block's private contiguous ssrc region (single-L2 merge).
__global__ void fillb_k(const uint2* __restrict__ ebuf, const int* __restrict__ row_off,
                        int* __restrict__ ssrc, int n) {
  __shared__ int lcur[1 << BKT_SH];
  const int b = blockIdx.x, t = threadIdx.x;
  const int v0 = b << BKT_SH;
  const int nv = min(1 << BKT_SH, n - v0);
  if (t < nv) lcur[t] = row_off[v0 + t];
  __syncthreads();
  const int start = row_off[v0];
  const int end   = row_off[v0 + nv];
  for (int i = start + t; i < end; i += 256) {
    const uint2 e = ebuf[i];
    const int p = atomicAdd(&lcur[e.y & ((1 << BKT_SH) - 1)], 1);
    ssrc[p] = (int)e.x;
  }
}

// ---------------- fused gather + MFMA GEMM (+relu | +log_softmax) ----------
template <int DOUT, bool LS>
__launch_bounds__(256, 4)
__global__ void fused_k(const unsigned short* __restrict__ in,
                        const int* __restrict__ row_off, const int* __restrict__ ssrc,
                        const float* __restrict__ Wm, const float* __restrict__ bin,
                        void* __restrict__ outp, int n) {
  constexpr int NT = (DOUT + 15) / 16;
  const int lane  = threadIdx.x & 63;
  const int wslot = threadIdx.x >> 6;
  const int quad  = lane >> 4;
  const int f16i  = lane & 15;

  __shared__ char smem_raw[4][16 * 144];
  char* my = smem_raw[wslot];

  // B fragments: W (bf16) in registers, 2 K-steps x NT col tiles.
  bf8 bfr[2][NT];
#pragma unroll
  for (int s = 0; s < 2; ++s)
#pragma unroll
    for (int t = 0; t < NT; ++t) {
      const int c = t * 16 + f16i;
#pragma unroll
      for (int j = 0; j < 8; ++j) {
        const int k = s * 32 + quad * 8 + j;
        float wv = (c < DOUT) ? Wm[k * DOUT + c] : 0.f;
        bfr[s][t][j] = (short)f2bf(wv);
      }
    }
  float bc[NT];
#pragma unroll
  for (int t = 0; t < NT; ++t) {
    const int c = t * 16 + f16i;
    bc[t] = (c < DOUT) ? bin[c] : 0.f;
  }

  const uint2* in2 = (const uint2*)in;     // bf16 row = 16 x uint2 (128B)
  const int wid = (int)((blockIdx.x * blockDim.x + threadIdx.x) >> 6);
  const int nwv = (int)((gridDim.x * blockDim.x) >> 6);
  const int ntiles = (n + 15) >> 4;

  for (int tile = wid; tile < ntiles; tile += nwv) {
    const int v0 = tile << 4;
    // ---- gather 16 node-sums -> bf16 rows in LDS (4 edges/iter) ----
#pragma unroll
    for (int r = 0; r < 4; ++r) {
      const int m = quad * 4 + r;
      const int v = v0 + m;
      int start = 0, end = 0;
      if (v < n) { start = row_off[v]; end = row_off[v + 1]; }
      float4 a0 = make_float4(0.f, 0.f, 0.f, 0.f);
      float4 a1 = make_float4(0.f, 0.f, 0.f, 0.f);
      for (int c = start; c < end; c += 4) {
        const bool h1 = (c + 1) < end, h2 = (c + 2) < end, h3 = (c + 3) < end;
        const int s0 = ssrc[c];
        const int s1 = h1 ? ssrc[c + 1] : s0;
        const int s2 = h2 ? ssrc[c + 2] : s0;
        const int s3 = h3 ? ssrc[c + 3] : s0;
        uint2 q0 = in2[(size_t)s0 * 16 + f16i];
        uint2 q1 = h1 ? in2[(size_t)s1 * 16 + f16i] : make_uint2(0u, 0u);
        uint2 q2 = h2 ? in2[(size_t)s2 * 16 + f16i] : make_uint2(0u, 0u);
        uint2 q3 = h3 ? in2[(size_t)s3 * 16 + f16i] : make_uint2(0u, 0u);
        a0.x += bflo(q0.x) + bflo(q2.x); a1.x += bflo(q1.x) + bflo(q3.x);
        a0.y += bfhi(q0.x) + bfhi(q2.x); a1.y += bfhi(q1.x) + bfhi(q3.x);
        a0.z += bflo(q0.y) + bflo(q2.y); a1.z += bflo(q1.y) + bflo(q3.y);
        a0.w += bfhi(q0.y) + bfhi(q2.y); a1.w += bfhi(q1.y) + bfhi(q3.y);
      }
      uint2 p;
      p.x = f2bf(a0.x + a1.x) | (f2bf(a0.y + a1.y) << 16);
      p.y = f2bf(a0.z + a1.z) | (f2bf(a0.w + a1.w) << 16);
      *(uint2*)(my + m * 144 + f16i * 8) = p;
    }
    asm volatile("s_waitcnt lgkmcnt(0)" ::: "memory");  // cross-lane LDS RAW

    // ---- MFMA: [16 x 64] @ [64 x DOUT] ----
    bf8 a0 = *(const bf8*)(my + f16i * 144 + quad * 16);        // K 0..31
    bf8 a1 = *(const bf8*)(my + f16i * 144 + quad * 16 + 64);   // K 32..63
    f4 acc[NT];
#pragma unroll
    for (int t = 0; t < NT; ++t) {
      f4 z = {0.f, 0.f, 0.f, 0.f};
      acc[t] = __builtin_amdgcn_mfma_f32_16x16x32_bf16(a0, bfr[0][t], z, 0, 0, 0);
      acc[t] = __builtin_amdgcn_mfma_f32_16x16x32_bf16(a1, bfr[1][t], acc[t], 0, 0, 0);
    }

    // ---- epilogue ----
    if (!LS) {
      unsigned short* ob = (unsigned short*)outp;
#pragma unroll
      for (int t = 0; t < NT; ++t)
#pragma unroll
        for (int j = 0; j < 4; ++j) {
          const int v = v0 + quad * 4 + j;
          if (v < n) {
            float val = acc[t][j] + bc[t];
            ob[(size_t)v * 64 + t * 16 + f16i] =
                (unsigned short)f2bf(fmaxf(val, 0.f));
          }
        }
    } else {
      float* ob = (float*)outp;
      float val[NT][4];
#pragma unroll
      for (int t = 0; t < NT; ++t)
#pragma unroll
        for (int j = 0; j < 4; ++j) val[t][j] = acc[t][j] + bc[t];
#pragma unroll
      for (int j = 0; j < 4; ++j) {
        float mx = -INFINITY;
#pragma unroll
        for (int t = 0; t < NT; ++t)
          if (t * 16 + f16i < DOUT) mx = fmaxf(mx, val[t][j]);
#pragma unroll
        for (int o = 1; o <= 8; o <<= 1) mx = fmaxf(mx, __shfl_xor(mx, o, 64));
        float sm = 0.f;
#pragma unroll
        for (int t = 0; t < NT; ++t)
          if (t * 16 + f16i < DOUT) sm += __expf(val[t][j] - mx);
#pragma unroll
        for (int o = 1; o <= 8; o <<= 1) sm += __shfl_xor(sm, o, 64);
        const float lse = mx + __logf(sm);
        const int v = v0 + quad * 4 + j;
        if (v < n) {
#pragma unroll
          for (int t = 0; t < NT; ++t) {
            const int c = t * 16 + f16i;
            if (c < DOUT) ob[(size_t)v * DOUT + c] = val[t][j] - lse;
          }
        }
      }
    }
  }
}

extern "C" void kernel_launch(void* const* d_in, const int* in_sizes, int n_in,
                              void* d_out, int out_size, void* d_ws, size_t ws_size,
                              hipStream_t stream) {
  const float* x  = (const float*)d_in[0];
  const int*   ei = (const int*)d_in[1];   // [2, E] int32, row-major
  const float* W1 = (const float*)d_in[2];
  const float* b1 = (const float*)d_in[3];
  const float* W2 = (const float*)d_in[4];
  const float* b2 = (const float*)d_in[5];
  const float* W3 = (const float*)d_in[6];
  const float* b3 = (const float*)d_in[7];
  float* outp = (float*)d_out;

  const int n  = in_sizes[0] / 64;   // 100000
  const int ne = in_sizes[1] / 2;    // 800000
  const int* srci = ei;
  const int* dsti = ei + ne;
  const int nbkt = (n + (1 << BKT_SH) - 1) >> BKT_SH;   // 391

  const size_t N64 = (size_t)n * 64;
  unsigned short* xb   = (unsigned short*)d_ws;   // N*64 bf16
  unsigned short* bufA = xb + N64;                // N*64 bf16 (h1)
  unsigned short* bufB = bufA + N64;              // N*64 bf16 (h2)
  uint2* ebuf   = (uint2*)(bufB + N64);           // E x (src,dst), 8B aligned
  int* cnt      = (int*)(ebuf + ne);              // N
  int* row_off  = cnt + n;                        // N+1
  int* bsum     = row_off + n + 1;                // 512
  int* bcur     = bsum + 512;                     // 512
  int* ssrc     = bcur + 512;                     // E

  const int TB = 256;
  const int nscan = (n + SCAN_B - 1) / SCAN_B;
  const int b1_blocks = (ne + B1_EPB - 1) / B1_EPB;   // 98
  const int fus_blocks = 1568;                        // 1 tile/wave (6250 tiles)

  // ---- CSR build + x->bf16 ----
  hipMemsetAsync(cnt, 0, (size_t)n * sizeof(int), stream);
  hist_cvt_k<<<2048, TB, 0, stream>>>(dsti, cnt, ne, x, xb, (int)(N64 / 4));
  scan1_k<<<nscan, SCAN_B, 0, stream>>>(cnt, bsum, n);
  scan23_k<<<nscan, SCAN_B, 0, stream>>>(cnt, bsum, row_off, bcur, n, ne);
  bucket_k<<<b1_blocks, TB, 0, stream>>>(srci, dsti, bcur, ebuf, ne, nbkt);
  fillb_k<<<nbkt, TB, 0, stream>>>(ebuf, row_off, ssrc, n);

  // ---- fused layers ----
  fused_k<64, false><<<fus_blocks, TB, 0, stream>>>(xb,   row_off, ssrc, W1, b1, bufA, n);
  fused_k<64, false><<<fus_blocks, TB, 0, stream>>>(bufA, row_off, ssrc, W2, b2, bufB, n);
  fused_k<47, true ><<<fus_blocks, TB, 0, stream>>>(bufB, row_off, ssrc, W3, b3, outp, n);
}

// Round 7
// 231.793 us; speedup vs baseline: 1.7417x; 1.2143x over previous
//
#include <hip/hip_runtime.h>
#include <cmath>

// ---------------------------------------------------------------------------
// 3-layer GCN, atomic-free aggregate, bf16 data path, MFMA epilogue.
// CSR build: hist+cvt -> scan1 -> scan23 -> bucket_k -> fillb_k (2-level fill:
// every ssrc/ebuf line is single-block-owned; R5 showed random 4B stores cost
// a full 64B HBM line each otherwise).
// Fused layer (R7): stage tile's edge indices into LDS (coalesced, one wait),
// then 8 independent row-loads in flight per quarter -> fp32 accumulate ->
// bf16 rows in LDS -> mfma_f32_16x16x32_bf16 -> bias (+relu | +log_softmax).
// R6 was latency-bound (VALU 22%, HBM 15%): per-edge ssrc->row dependent
// chains gave only ~4 loads in flight; LDS-staged indices break the chain.
// ---------------------------------------------------------------------------

#define SCAN_B 256
#define B1_EPB 4096      // edges per bucket_k block (196 blocks)
#define BKT_SH 8         // 256 nodes per bucket
#define CHUNK  256       // staged edge indices per wave-chunk

typedef __attribute__((ext_vector_type(8))) short bf8;   // 8 x bf16 (4 VGPR)
typedef __attribute__((ext_vector_type(4))) float f4;    // MFMA accumulator

__device__ __forceinline__ unsigned int f2bf(float x) {  // RNE
  unsigned int u = __float_as_uint(x);
  return (u + 0x7FFFu + ((u >> 16) & 1u)) >> 16;
}
__device__ __forceinline__ float bflo(unsigned int u) { return __uint_as_float(u << 16); }
__device__ __forceinline__ float bfhi(unsigned int u) { return __uint_as_float(u & 0xFFFF0000u); }

// ---------------- CSR build ----------------
__global__ void hist_cvt_k(const int* __restrict__ dsti, int* __restrict__ cnt, int ne,
                           const float* __restrict__ x, unsigned short* __restrict__ xb,
                           int n4) {
  int i = blockIdx.x * blockDim.x + threadIdx.x;
  int st = gridDim.x * blockDim.x;
  for (int e = i; e < ne; e += st) atomicAdd(&cnt[dsti[e]], 1);
  for (int j = i; j < n4; j += st) {
    float4 v = ((const float4*)x)[j];
    ushort4 o;
    o.x = (unsigned short)f2bf(v.x); o.y = (unsigned short)f2bf(v.y);
    o.z = (unsigned short)f2bf(v.z); o.w = (unsigned short)f2bf(v.w);
    ((ushort4*)xb)[j] = o;
  }
}

__global__ void scan1_k(int* __restrict__ cnt, int* __restrict__ bsum, int n) {
  __shared__ int sh[SCAN_B];
  int t = threadIdx.x, i = blockIdx.x * SCAN_B + t;
  int x = (i < n) ? cnt[i] : 0;
  sh[t] = x; __syncthreads();
  for (int o = 1; o < SCAN_B; o <<= 1) {
    int v = (t >= o) ? sh[t - o] : 0; __syncthreads();
    sh[t] += v; __syncthreads();
  }
  if (i < n) cnt[i] = sh[t] - x;           // exclusive within block
  if (t == SCAN_B - 1) bsum[blockIdx.x] = sh[t];
}

// row_off[i] = cnt[i] + sum(bsum[0..block)), bcur[b] = row_off[b*256]
__global__ void scan23_k(const int* __restrict__ cnt, const int* __restrict__ bsum,
                         int* __restrict__ row_off, int* __restrict__ bcur,
                         int n, int ne) {
  __shared__ int sh[SCAN_B];
  const int b = blockIdx.x, t = threadIdx.x;
  int s = 0;
  for (int j = t; j < b; j += SCAN_B) s += bsum[j];
  sh[t] = s; __syncthreads();
  for (int o = SCAN_B / 2; o > 0; o >>= 1) {
    if (t < o) sh[t] += sh[t + o];
    __syncthreads();
  }
  const int pref = sh[0];
  const int i = b * SCAN_B + t;
  if (i < n) {
    int v = cnt[i] + pref;
    row_off[i] = v;
    if ((i & ((1 << BKT_SH) - 1)) == 0) bcur[i >> BKT_SH] = v;
  }
  if (b == 0 && t == 0) row_off[n] = ne;
}

// Level 1: scatter (src,dst) into per-bucket regions of ebuf. Per-(block,bin)
// runs are contiguous & single-CU -> partial stores merge in that CU's L2.
__global__ void bucket_k(const int* __restrict__ srci, const int* __restrict__ dsti,
                         int* __restrict__ bcur, uint2* __restrict__ ebuf,
                         int ne, int nbkt) {
  __shared__ int lhist[512], lbase[512];
  const int t = threadIdx.x;
  const int base = blockIdx.x * B1_EPB;
  const int m = min(B1_EPB, ne - base);
  for (int i = t; i < nbkt; i += 256) lhist[i] = 0;
  __syncthreads();
  for (int i = t; i < m; i += 256) atomicAdd(&lhist[dsti[base + i] >> BKT_SH], 1);
  __syncthreads();
  for (int i = t; i < nbkt; i += 256) {
    int c = lhist[i];
    lbase[i] = c ? atomicAdd(&bcur[i], c) : 0;
  }
  __syncthreads();
  for (int i = t; i < nbkt; i += 256) lhist[i] = 0;   // reuse as local cursor
  __syncthreads();
  for (int i = t; i < m; i += 256) {
    const int s = srci[base + i], d = dsti[base + i];
    const int b = d >> BKT_SH;
    const int p = lbase[b] + atomicAdd(&lhist[b], 1);
    ebuf[p] = make_uint2((unsigned)s, (unsigned)d);
  }
}

// Level 2: one block per 256-node bucket; LDS per-node cursors; writes land
// in this block's private contiguous ssrc region (single-L2 merge).
__global__ void fillb_k(const uint2* __restrict__ ebuf, const int* __restrict__ row_off,
                        int* __restrict__ ssrc, int n) {
  __shared__ int lcur[1 << BKT_SH];
  const int b = blockIdx.x, t = threadIdx.x;
  const int v0 = b << BKT_SH;
  const int nv = min(1 << BKT_SH, n - v0);
  if (t < nv) lcur[t] = row_off[v0 + t];
  __syncthreads();
  const int start = row_off[v0];
  const int end   = row_off[v0 + nv];
  for (int i = start + t; i < end; i += 256) {
    const uint2 e = ebuf[i];
    const int p = atomicAdd(&lcur[e.y & ((1 << BKT_SH) - 1)], 1);
    ssrc[p] = (int)e.x;
  }
}

// ---------------- fused gather + MFMA GEMM (+relu | +log_softmax) ----------
// One wave per 16-node tile. Edge indices for the tile staged into LDS in
// CHUNK-sized pieces (coalesced); then each quarter q gathers its 4 nodes
// (m = q*4+r) with 8 independent row loads in flight; rows -> LDS (144B
// stride) -> MFMA. C layout: col = lane&15, row = quad*4 + reg.
template <int DOUT, bool LS>
__launch_bounds__(256, 4)
__global__ void fused_k(const unsigned short* __restrict__ in,
                        const int* __restrict__ row_off, const int* __restrict__ ssrc,
                        const float* __restrict__ Wm, const float* __restrict__ bin,
                        void* __restrict__ outp, int n) {
  constexpr int NT = (DOUT + 15) / 16;
  const int lane  = threadIdx.x & 63;
  const int wslot = threadIdx.x >> 6;
  const int quad  = lane >> 4;
  const int f16i  = lane & 15;

  __shared__ char rows_raw[4][16 * 144];
  __shared__ int  sidx[4][CHUNK];
  char* my  = rows_raw[wslot];
  int*  sid = sidx[wslot];

  // B fragments: W (bf16) in registers, 2 K-steps x NT col tiles.
  bf8 bfr[2][NT];
#pragma unroll
  for (int s = 0; s < 2; ++s)
#pragma unroll
    for (int t = 0; t < NT; ++t) {
      const int c = t * 16 + f16i;
#pragma unroll
      for (int j = 0; j < 8; ++j) {
        const int k = s * 32 + quad * 8 + j;
        float wv = (c < DOUT) ? Wm[k * DOUT + c] : 0.f;
        bfr[s][t][j] = (short)f2bf(wv);
      }
    }
  float bc[NT];
#pragma unroll
  for (int t = 0; t < NT; ++t) {
    const int c = t * 16 + f16i;
    bc[t] = (c < DOUT) ? bin[c] : 0.f;
  }

  const uint2* in2 = (const uint2*)in;     // bf16 row = 16 x uint2 (128B)
  const int wid = (int)((blockIdx.x * blockDim.x + threadIdx.x) >> 6);
  const int nwv = (int)((gridDim.x * blockDim.x) >> 6);
  const int ntiles = (n + 15) >> 4;

  for (int tile = wid; tile < ntiles; tile += nwv) {
    const int v0 = tile << 4;
    // per-node ranges via one lane-load + shuffles
    const int ro_l = row_off[min(v0 + min(lane, 16), n)];
    const int base     = __shfl(ro_l, 0, 64);
    const int tile_end = __shfl(ro_l, 16, 64);
    int ns[4], nE[4];
#pragma unroll
    for (int r = 0; r < 4; ++r) {
      const int m = quad * 4 + r;
      ns[r] = __shfl(ro_l, m, 64);
      nE[r] = __shfl(ro_l, m + 1, 64);
    }

    float4 accA[4], accB[4];
#pragma unroll
    for (int r = 0; r < 4; ++r) {
      accA[r] = make_float4(0.f, 0.f, 0.f, 0.f);
      accB[r] = make_float4(0.f, 0.f, 0.f, 0.f);
    }

    for (int off = base; off < tile_end; off += CHUNK) {
      const int cend = min(tile_end, off + CHUNK);
      const int nL = cend - off;
      // stage indices: coalesced, 4 guarded rounds
#pragma unroll
      for (int k = 0; k < CHUNK / 64; ++k) {
        const int p = off + lane + k * 64;
        if (p < cend) sid[lane + k * 64] = ssrc[p];
      }
      asm volatile("s_waitcnt lgkmcnt(0)" ::: "memory");   // cross-lane LDS RAW

#pragma unroll
      for (int r = 0; r < 4; ++r) {
        const int ls = max(ns[r], off), le = min(nE[r], cend);
        for (int c = ls; c < le; c += 8) {
          uint2 q[8];
#pragma unroll
          for (int k = 0; k < 8; ++k) {
            const int lofs = min(c - off + k, nL - 1);   // clamp LDS read
            const int s = sid[lofs];                      // quarter-broadcast
            q[k] = (c + k < le) ? in2[(size_t)s * 16 + f16i]
                                : make_uint2(0u, 0u);
          }
#pragma unroll
          for (int k = 0; k < 8; k += 2) {
            accA[r].x += bflo(q[k].x); accB[r].x += bflo(q[k + 1].x);
            accA[r].y += bfhi(q[k].x); accB[r].y += bfhi(q[k + 1].x);
            accA[r].z += bflo(q[k].y); accB[r].z += bflo(q[k + 1].y);
            accA[r].w += bfhi(q[k].y); accB[r].w += bfhi(q[k + 1].y);
          }
        }
      }
    }

    // pack rows -> LDS
#pragma unroll
    for (int r = 0; r < 4; ++r) {
      const int m = quad * 4 + r;
      uint2 p;
      p.x = f2bf(accA[r].x + accB[r].x) | (f2bf(accA[r].y + accB[r].y) << 16);
      p.y = f2bf(accA[r].z + accB[r].z) | (f2bf(accA[r].w + accB[r].w) << 16);
      *(uint2*)(my + m * 144 + f16i * 8) = p;
    }
    asm volatile("s_waitcnt lgkmcnt(0)" ::: "memory");   // cross-lane LDS RAW

    // ---- MFMA: [16 x 64] @ [64 x DOUT] ----
    bf8 a0 = *(const bf8*)(my + f16i * 144 + quad * 16);        // K 0..31
    bf8 a1 = *(const bf8*)(my + f16i * 144 + quad * 16 + 64);   // K 32..63
    f4 acc[NT];
#pragma unroll
    for (int t = 0; t < NT; ++t) {
      f4 z = {0.f, 0.f, 0.f, 0.f};
      acc[t] = __builtin_amdgcn_mfma_f32_16x16x32_bf16(a0, bfr[0][t], z, 0, 0, 0);
      acc[t] = __builtin_amdgcn_mfma_f32_16x16x32_bf16(a1, bfr[1][t], acc[t], 0, 0, 0);
    }

    // ---- epilogue ----
    if (!LS) {
      unsigned short* ob = (unsigned short*)outp;
#pragma unroll
      for (int t = 0; t < NT; ++t)
#pragma unroll
        for (int j = 0; j < 4; ++j) {
          const int v = v0 + quad * 4 + j;
          if (v < n) {
            float val = acc[t][j] + bc[t];
            ob[(size_t)v * 64 + t * 16 + f16i] =
                (unsigned short)f2bf(fmaxf(val, 0.f));
          }
        }
    } else {
      float* ob = (float*)outp;
      float val[NT][4];
#pragma unroll
      for (int t = 0; t < NT; ++t)
#pragma unroll
        for (int j = 0; j < 4; ++j) val[t][j] = acc[t][j] + bc[t];
#pragma unroll
      for (int j = 0; j < 4; ++j) {
        float mx = -INFINITY;
#pragma unroll
        for (int t = 0; t < NT; ++t)
          if (t * 16 + f16i < DOUT) mx = fmaxf(mx, val[t][j]);
#pragma unroll
        for (int o = 1; o <= 8; o <<= 1) mx = fmaxf(mx, __shfl_xor(mx, o, 64));
        float sm = 0.f;
#pragma unroll
        for (int t = 0; t < NT; ++t)
          if (t * 16 + f16i < DOUT) sm += __expf(val[t][j] - mx);
#pragma unroll
        for (int o = 1; o <= 8; o <<= 1) sm += __shfl_xor(sm, o, 64);
        const float lse = mx + __logf(sm);
        const int v = v0 + quad * 4 + j;
        if (v < n) {
#pragma unroll
          for (int t = 0; t < NT; ++t) {
            const int c = t * 16 + f16i;
            if (c < DOUT) ob[(size_t)v * DOUT + c] = val[t][j] - lse;
          }
        }
      }
    }
  }
}

extern "C" void kernel_launch(void* const* d_in, const int* in_sizes, int n_in,
                              void* d_out, int out_size, void* d_ws, size_t ws_size,
                              hipStream_t stream) {
  const float* x  = (const float*)d_in[0];
  const int*   ei = (const int*)d_in[1];   // [2, E] int32, row-major
  const float* W1 = (const float*)d_in[2];
  const float* b1 = (const float*)d_in[3];
  const float* W2 = (const float*)d_in[4];
  const float* b2 = (const float*)d_in[5];
  const float* W3 = (const float*)d_in[6];
  const float* b3 = (const float*)d_in[7];
  float* outp = (float*)d_out;

  const int n  = in_sizes[0] / 64;   // 100000
  const int ne = in_sizes[1] / 2;    // 800000
  const int* srci = ei;
  const int* dsti = ei + ne;
  const int nbkt = (n + (1 << BKT_SH) - 1) >> BKT_SH;   // 391

  const size_t N64 = (size_t)n * 64;
  unsigned short* xb   = (unsigned short*)d_ws;   // N*64 bf16
  unsigned short* bufA = xb + N64;                // N*64 bf16 (h1)
  unsigned short* bufB = bufA + N64;              // N*64 bf16 (h2)
  uint2* ebuf   = (uint2*)(bufB + N64);           // E x (src,dst)
  int* cnt      = (int*)(ebuf + ne);              // N
  int* row_off  = cnt + n;                        // N+1
  int* bsum     = row_off + n + 1;                // 512
  int* bcur     = bsum + 512;                     // 512
  int* ssrc     = bcur + 512;                     // E

  const int TB = 256;
  const int nscan = (n + SCAN_B - 1) / SCAN_B;
  const int b1_blocks = (ne + B1_EPB - 1) / B1_EPB;   // 196
  const int fus_blocks = 1568;                        // 1 tile/wave (6250 tiles)

  // ---- CSR build + x->bf16 ----
  hipMemsetAsync(cnt, 0, (size_t)n * sizeof(int), stream);
  hist_cvt_k<<<2048, TB, 0, stream>>>(dsti, cnt, ne, x, xb, (int)(N64 / 4));
  scan1_k<<<nscan, SCAN_B, 0, stream>>>(cnt, bsum, n);
  scan23_k<<<nscan, SCAN_B, 0, stream>>>(cnt, bsum, row_off, bcur, n, ne);
  bucket_k<<<b1_blocks, TB, 0, stream>>>(srci, dsti, bcur, ebuf, ne, nbkt);
  fillb_k<<<nbkt, TB, 0, stream>>>(ebuf, row_off, ssrc, n);

  // ---- fused layers ----
  fused_k<64, false><<<fus_blocks, TB, 0, stream>>>(xb,   row_off, ssrc, W1, b1, bufA, n);
  fused_k<64, false><<<fus_blocks, TB, 0, stream>>>(bufA, row_off, ssrc, W2, b2, bufB, n);
  fused_k<47, true ><<<fus_blocks, TB, 0, stream>>>(bufB, row_off, ssrc, W3, b3, outp, n);
}